// Round 6
// baseline (358.010 us; speedup 1.0000x reference)
//
#include <hip/hip_runtime.h>

// Problem: out0, out1, targets: [16, 21, 256, 256] f32; out2: [16, 21] f32.
// Output: scalar f32 = mean(bce(out0,t)) + 0.4*mean(bce(out1,t)) + 0.2*mean(bce(out2, presence)).
//
// R5 established: nontemporal (nt) loads are mandatory here — cached float4
// streams serialize on L1 set/MSHR resources (4 kernel structures all pinned
// at ~100 us, even when inputs were fully L2/L3-resident; nt loads broke the
// kernel below the 52-us harness fill dispatches).
constexpr int kB = 16;
constexpr int kC = 21;
constexpr int kPerSample = kC * 256 * 256;                    // 1376256
constexpr int kN = kB * kPerSample;                           // 22020096
constexpr int kF4PerSample = kPerSample / 4;                  // 344064
constexpr int kIters = 8;                                     // float4 per thread
constexpr int kF4PerBlock = kIters * 256;                     // 2048
constexpr int kBlocksPerSample = kF4PerSample / kF4PerBlock;  // 168
constexpr int kGrid = kB * kBlocksPerSample;                  // 2688 blocks

// Clang ext vector so __builtin_nontemporal_load works (HIP float4 is a struct).
typedef float f32x4 __attribute__((ext_vector_type(4)));

// Stable BCE-with-logits term: max(x,0) - x*t + log(1+exp(-|x|)).
__device__ __forceinline__ float bce_term(float x, float t) {
    return fmaf(-t, x, fmaxf(x, 0.0f)) + __logf(1.0f + __expf(-fabsf(x)));
}

__device__ __forceinline__ float bce4(f32x4 x, f32x4 t) {
    return bce_term(x.x, t.x) + bce_term(x.y, t.y)
         + bce_term(x.z, t.z) + bce_term(x.w, t.w);
}

// torch.histc semantics: bin_w = 20/21, idx = clip(floor(x/bin_w), 0, 20),
// values outside [0, 20] dropped. Trimmed to ~7 VALU ops:
// cvt_flr+mul, med3 clamp, 2 cmp, shl, cndmask, or.
__device__ __forceinline__ unsigned int histbit(float x) {
    int u = (int)floorf(x * (21.0f / 20.0f));
    u = min(max(u, 0), 20);                       // v_med3_i32
    unsigned int bit = 1u << u;
    return (x >= 0.0f && x <= 20.0f) ? bit : 0u;  // histc drops out-of-range
}

// Single fused kernel. Each block owns a contiguous 2048-float4 chunk of one
// sample; nt float4 loads; block partials to workspace; last-arriving block
// (threadfence-reduction pattern, device-scope so XCD-safe) folds the 2688
// partials, computes the 336-element SE BCE, and writes the scalar.
__global__ __launch_bounds__(256) void fused_loss(
    const f32x4* __restrict__ o0, const f32x4* __restrict__ o1,
    const f32x4* __restrict__ tg, const float* __restrict__ out2,
    float* __restrict__ out, unsigned int* __restrict__ counter,
    float* __restrict__ part_sum, unsigned int* __restrict__ part_mask)
{
    const int tid = threadIdx.x;
    const int blk = blockIdx.x;
    const int samp = blk / kBlocksPerSample;
    const int chunk = blk - samp * kBlocksPerSample;
    const int base = samp * kF4PerSample + chunk * kF4PerBlock + tid;

    float acc0 = 0.0f, acc1 = 0.0f;
    unsigned int m = 0u;

    #pragma unroll
    for (int k = 0; k < kIters; ++k) {
        const int idx = base + k * 256;
        f32x4 a = __builtin_nontemporal_load(&o0[idx]);
        f32x4 b = __builtin_nontemporal_load(&o1[idx]);
        f32x4 t = __builtin_nontemporal_load(&tg[idx]);
        acc0 += bce4(a, t);
        acc1 += bce4(b, t);
        m |= histbit(t.x) | histbit(t.y) | histbit(t.z) | histbit(t.w);
    }
    float acc = acc0 + 0.4f * acc1;

    // Wave64 shuffle reduction for sum and mask, then cross-wave via LDS.
    #pragma unroll
    for (int off = 32; off >= 1; off >>= 1) {
        acc += __shfl_down(acc, off, 64);
        m |= (unsigned int)__shfl_down((int)m, off, 64);
    }
    __shared__ float s_red[4];
    __shared__ unsigned int s_m[4];
    __shared__ bool s_last;
    if ((tid & 63) == 0) { s_red[tid >> 6] = acc; s_m[tid >> 6] = m; }
    __syncthreads();
    if (tid == 0) {
        part_sum[blk] = s_red[0] + s_red[1] + s_red[2] + s_red[3];
        part_mask[blk] = s_m[0] | s_m[1] | s_m[2] | s_m[3];
        __threadfence();                          // release partials (device scope)
        unsigned int prev = atomicAdd(counter, 1u);
        s_last = (prev == (unsigned int)(kGrid - 1));
    }
    __syncthreads();
    if (!s_last) return;

    // ---- Last block only: final reduction + SE term + combine. ----
    __threadfence();                              // acquire other blocks' partials
    __shared__ unsigned int s_mask[kB];
    if (tid < kB) s_mask[tid] = 0u;
    __syncthreads();

    float tot = 0.0f;
    for (int i = tid; i < kGrid; i += 256) {
        tot += part_sum[i];
        unsigned int mm = part_mask[i];
        int s = i / kBlocksPerSample;
        if (mm & ~s_mask[s]) atomicOr(&s_mask[s], mm);
    }
    #pragma unroll
    for (int off = 32; off >= 1; off >>= 1)
        tot += __shfl_down(tot, off, 64);
    if ((tid & 63) == 0) s_red[tid >> 6] = tot;
    __syncthreads();                              // also orders s_mask atomics

    float se = 0.0f;
    for (int i = tid; i < kB * kC; i += 256) {    // 336 > 256: loop
        int b = i / kC;
        int c = i - b * kC;
        se += bce_term(out2[i], (float)((s_mask[b] >> c) & 1u));
    }
    #pragma unroll
    for (int off = 32; off >= 1; off >>= 1)
        se += __shfl_down(se, off, 64);
    __shared__ float s_se[4];
    if ((tid & 63) == 0) s_se[tid >> 6] = se;
    __syncthreads();

    if (tid == 0) {
        float main_total = s_red[0] + s_red[1] + s_red[2] + s_red[3];
        float se_total   = s_se[0] + s_se[1] + s_se[2] + s_se[3];
        out[0] = main_total * (1.0f / (float)kN)
               + 0.2f * (se_total / (float)(kB * kC));
    }
}

extern "C" void kernel_launch(void* const* d_in, const int* in_sizes, int n_in,
                              void* d_out, int out_size, void* d_ws, size_t ws_size,
                              hipStream_t stream) {
    const float* out0    = (const float*)d_in[0];
    const float* out1    = (const float*)d_in[1];
    const float* out2    = (const float*)d_in[2];
    const float* targets = (const float*)d_in[3];

    unsigned int* counter   = (unsigned int*)d_ws;                  // 1 uint
    float*        part_sum  = (float*)((char*)d_ws + 1024);         // kGrid floats
    unsigned int* part_mask = (unsigned int*)((char*)d_ws + 16384); // kGrid uints

    // ws is re-poisoned to 0xAA before every timed launch — zero the ticket.
    hipMemsetAsync(d_ws, 0, 64, stream);

    fused_loss<<<kGrid, 256, 0, stream>>>(
        (const f32x4*)out0, (const f32x4*)out1, (const f32x4*)targets,
        out2, (float*)d_out, counter, part_sum, part_mask);
}

// Round 7
// 228.206 us; speedup vs baseline: 1.5688x; 1.5688x over previous
//
#include <hip/hip_runtime.h>

// Problem: out0, out1, targets: [16, 21, 256, 256] f32; out2: [16, 21] f32.
// Output: scalar f32 = mean(bce(out0,t)) + 0.4*mean(bce(out1,t)) + 0.2*mean(bce(out2, presence)).
//
// Hard-won structural facts (R0-R6):
//  * nt (nontemporal) loads are MANDATORY: cached float4 streams serialize on
//    L1 set/MSHR resources — four kernel structures all pinned at ~100 us,
//    even with inputs fully L2/L3-resident. nt loads: <52 us (R5).
//  * Do NOT fuse the final reduction via per-block __threadfence() ticket:
//    device-scope fences emit buffer_wbl2/buffer_inv per block -> global
//    memory-pipeline poisoning, 2x regression (R6: 180 us, BW 1.47 TB/s).
//    Two dispatches with a ~5 us gap is far cheaper.
constexpr int kB = 16;
constexpr int kC = 21;
constexpr int kPerSample = kC * 256 * 256;                    // 1376256
constexpr int kN = kB * kPerSample;                           // 22020096
constexpr int kF4PerSample = kPerSample / 4;                  // 344064
constexpr int kIters = 8;                                     // float4 per thread
constexpr int kF4PerBlock = kIters * 256;                     // 2048
constexpr int kBlocksPerSample = kF4PerSample / kF4PerBlock;  // 168
constexpr int kGrid = kB * kBlocksPerSample;                  // 2688 blocks

// Clang ext vector so __builtin_nontemporal_load works (HIP float4 is a struct).
typedef float f32x4 __attribute__((ext_vector_type(4)));

// Stable BCE-with-logits term: max(x,0) - x*t + log(1+exp(-|x|)).
__device__ __forceinline__ float bce_term(float x, float t) {
    return fmaf(-t, x, fmaxf(x, 0.0f)) + __logf(1.0f + __expf(-fabsf(x)));
}

__device__ __forceinline__ float bce4(f32x4 x, f32x4 t) {
    return bce_term(x.x, t.x) + bce_term(x.y, t.y)
         + bce_term(x.z, t.z) + bce_term(x.w, t.w);
}

// torch.histc semantics: bin_w = 20/21, idx = clip(floor(x/bin_w), 0, 20),
// values outside [0, 20] dropped. ~7 VALU ops: mul+cvt_flr, med3, shl,
// 2 cmp, cndmask, or.
__device__ __forceinline__ unsigned int histbit(float x) {
    int u = (int)floorf(x * (21.0f / 20.0f));
    u = min(max(u, 0), 20);                       // v_med3_i32
    unsigned int bit = 1u << u;
    return (x >= 0.0f && x <= 20.0f) ? bit : 0u;  // histc drops out-of-range
}

// Kernel 1 (R5-proven): each block owns a contiguous 2048-float4 chunk of ONE
// sample; nt float4 loads; per-block partial sum + class-presence mask written
// to distinct workspace slots (no atomics, no fences, no zero-init needed).
__global__ __launch_bounds__(256) void main_reduce(
    const f32x4* __restrict__ o0, const f32x4* __restrict__ o1,
    const f32x4* __restrict__ tg, float* __restrict__ part_sum,
    unsigned int* __restrict__ part_mask)
{
    const int tid = threadIdx.x;
    const int blk = blockIdx.x;
    const int samp = blk / kBlocksPerSample;
    const int chunk = blk - samp * kBlocksPerSample;
    const int base = samp * kF4PerSample + chunk * kF4PerBlock + tid;

    float acc0 = 0.0f, acc1 = 0.0f;
    unsigned int m = 0u;

    #pragma unroll
    for (int k = 0; k < kIters; ++k) {
        const int idx = base + k * 256;
        f32x4 a = __builtin_nontemporal_load(&o0[idx]);
        f32x4 b = __builtin_nontemporal_load(&o1[idx]);
        f32x4 t = __builtin_nontemporal_load(&tg[idx]);
        acc0 += bce4(a, t);
        acc1 += bce4(b, t);
        m |= histbit(t.x) | histbit(t.y) | histbit(t.z) | histbit(t.w);
    }
    float acc = acc0 + 0.4f * acc1;

    // Wave64 shuffle reduction for both sum and mask, then cross-wave via LDS.
    #pragma unroll
    for (int off = 32; off >= 1; off >>= 1) {
        acc += __shfl_down(acc, off, 64);
        m |= (unsigned int)__shfl_down((int)m, off, 64);
    }
    __shared__ float s_red[4];
    __shared__ unsigned int s_m[4];
    if ((tid & 63) == 0) { s_red[tid >> 6] = acc; s_m[tid >> 6] = m; }
    __syncthreads();
    if (tid == 0) {
        part_sum[blk] = s_red[0] + s_red[1] + s_red[2] + s_red[3];
        part_mask[blk] = s_m[0] | s_m[1] | s_m[2] | s_m[3];
    }
}

// Kernel 2: reduce 2688 partials, build per-sample presence vectors,
// compute the 336-element SE BCE, combine all three loss terms.
__global__ __launch_bounds__(1024) void finish_kernel(
    const float* __restrict__ out2, const float* __restrict__ part_sum,
    const unsigned int* __restrict__ part_mask, float* __restrict__ out)
{
    __shared__ unsigned int s_mask[kB];
    __shared__ float s_red[16];
    __shared__ float s_red2[16];
    const int tid = threadIdx.x;
    if (tid < kB) s_mask[tid] = 0u;
    __syncthreads();

    float acc = 0.0f;
    for (int i = tid; i < kGrid; i += 1024) {
        acc += part_sum[i];
        unsigned int m = part_mask[i];
        int s = i / kBlocksPerSample;
        if (m & ~s_mask[s]) atomicOr(&s_mask[s], m);
    }
    #pragma unroll
    for (int off = 32; off >= 1; off >>= 1)
        acc += __shfl_down(acc, off, 64);
    if ((tid & 63) == 0) s_red[tid >> 6] = acc;
    __syncthreads();  // also orders the s_mask atomics

    float se = 0.0f;
    if (tid < kB * kC) {
        int b = tid / kC;
        int c = tid - b * kC;
        float tv = (float)((s_mask[b] >> c) & 1u);
        se = bce_term(out2[tid], tv);
    }
    #pragma unroll
    for (int off = 32; off >= 1; off >>= 1)
        se += __shfl_down(se, off, 64);
    if ((tid & 63) == 0) s_red2[tid >> 6] = se;
    __syncthreads();

    if (tid == 0) {
        float main_total = 0.0f, se_total = 0.0f;
        #pragma unroll
        for (int w = 0; w < 16; ++w) { main_total += s_red[w]; se_total += s_red2[w]; }
        out[0] = main_total * (1.0f / (float)kN)
               + 0.2f * (se_total / (float)(kB * kC));
    }
}

extern "C" void kernel_launch(void* const* d_in, const int* in_sizes, int n_in,
                              void* d_out, int out_size, void* d_ws, size_t ws_size,
                              hipStream_t stream) {
    const float* out0    = (const float*)d_in[0];
    const float* out1    = (const float*)d_in[1];
    const float* out2    = (const float*)d_in[2];
    const float* targets = (const float*)d_in[3];

    float*        part_sum  = (float*)d_ws;                         // kGrid floats
    unsigned int* part_mask = (unsigned int*)((char*)d_ws + 16384); // kGrid uints

    main_reduce<<<kGrid, 256, 0, stream>>>(
        (const f32x4*)out0, (const f32x4*)out1, (const f32x4*)targets,
        part_sum, part_mask);
    finish_kernel<<<1, 1024, 0, stream>>>(out2, part_sum, part_mask, (float*)d_out);
}